// Round 10
// baseline (110.752 us; speedup 1.0000x reference)
//
#include <hip/hip_runtime.h>
#include <math.h>

#define BB 128
#define IN 1024
#define OUTD 1024
#define ISPLIT 16
#define ICHUNK (IN / ISPLIT)   // 64

typedef float f4v __attribute__((ext_vector_type(4)));

__device__ __forceinline__ float softplus(float r) {
    // stable: log(1+exp(r)) = max(r,0) + log1p(exp(-|r|))
    return fmaxf(r, 0.0f) + log1pf(expf(-fabsf(r)));
}

// sm[i][oq] = [softplus(ro) quad, mu quad] interleaved (8 floats per o-quad)
__global__ __launch_bounds__(256) void prep_sm(const float* __restrict__ ro,
                                               const float* __restrict__ mu,
                                               float* __restrict__ sm) {
    int idx = blockIdx.x * 256 + threadIdx.x;  // f4 index over IN*OUTD/4
    float4 r = ((const float4*)ro)[idx];
    float4 m = ((const float4*)mu)[idx];
    float4 s;
    s.x = softplus(r.x);
    s.y = softplus(r.y);
    s.z = softplus(r.z);
    s.w = softplus(r.w);
    ((float4*)sm)[idx * 2] = s;
    ((float4*)sm)[idx * 2 + 1] = m;
}

// Main: block = 4 b's x FULL o-range x ICHUNK i's. Thread tid owns float4 at
// o = tid*4 (4 waves span o=0..1023), with 4 eps streams (b0..b0+3) + 1 sm
// stream + 4 accumulators — R9's stream structure, but each 4 KB eps DRAM row
// is now consumed whole by one block (row opened once, not 4x).
// XCD swizzle: iblk = (bid&7) + 8*(t&1) -> each XCD owns 2 sm i-slices.
__global__ __launch_bounds__(256, 2) void bayes_main(
    const float* __restrict__ x, const float* __restrict__ eps,
    const float* __restrict__ sm, float* __restrict__ partial) {
    __shared__ float xs[4][ICHUNK];
    const int tid = threadIdx.x;

    // bijective decomposition; perf-only assumption bid%8 = XCD
    const int bid = blockIdx.x;            // [0,512)
    const int xcd = bid & 7;
    const int t = bid >> 3;                // [0,64)
    const int iblk = xcd + 8 * (t & 1);    // [0,16)
    const int bblk = t >> 1;               // [0,32)
    const int b0 = bblk * 4;
    const int i0 = iblk * ICHUNK;

    // stage x[b0..b0+3, i0..i0+ICHUNK-1] into LDS (256 floats, 256 threads)
    {
        int bb = tid >> 6, ii = tid & 63;
        xs[bb][ii] = x[(size_t)(b0 + bb) * IN + i0 + ii];
    }
    __syncthreads();

    const int o = tid * 4;

    const float4* smp = (const float4*)(sm + ((size_t)i0 * OUTD + o) * 2);
    const f4v* e0p = (const f4v*)(eps + ((size_t)(b0 + 0) * IN + i0) * OUTD + o);
    const f4v* e1p = (const f4v*)(eps + ((size_t)(b0 + 1) * IN + i0) * OUTD + o);
    const f4v* e2p = (const f4v*)(eps + ((size_t)(b0 + 2) * IN + i0) * OUTD + o);
    const f4v* e3p = (const f4v*)(eps + ((size_t)(b0 + 3) * IN + i0) * OUTD + o);

    float4 acc0 = {0.f, 0.f, 0.f, 0.f};
    float4 acc1 = {0.f, 0.f, 0.f, 0.f};
    float4 acc2 = {0.f, 0.f, 0.f, 0.f};
    float4 acc3 = {0.f, 0.f, 0.f, 0.f};

#pragma unroll 4
    for (int ii = 0; ii < ICHUNK; ++ii) {
        float4 s = smp[(size_t)ii * (OUTD / 2)];
        float4 m = smp[(size_t)ii * (OUTD / 2) + 1];
        f4v e0 = __builtin_nontemporal_load(e0p + (size_t)ii * (OUTD / 4));
        f4v e1 = __builtin_nontemporal_load(e1p + (size_t)ii * (OUTD / 4));
        f4v e2 = __builtin_nontemporal_load(e2p + (size_t)ii * (OUTD / 4));
        f4v e3 = __builtin_nontemporal_load(e3p + (size_t)ii * (OUTD / 4));
        float x0 = xs[0][ii];
        float x1 = xs[1][ii];
        float x2 = xs[2][ii];
        float x3 = xs[3][ii];
        acc0.x = fmaf(x0, fmaf(e0.x, s.x, m.x), acc0.x);
        acc0.y = fmaf(x0, fmaf(e0.y, s.y, m.y), acc0.y);
        acc0.z = fmaf(x0, fmaf(e0.z, s.z, m.z), acc0.z);
        acc0.w = fmaf(x0, fmaf(e0.w, s.w, m.w), acc0.w);
        acc1.x = fmaf(x1, fmaf(e1.x, s.x, m.x), acc1.x);
        acc1.y = fmaf(x1, fmaf(e1.y, s.y, m.y), acc1.y);
        acc1.z = fmaf(x1, fmaf(e1.z, s.z, m.z), acc1.z);
        acc1.w = fmaf(x1, fmaf(e1.w, s.w, m.w), acc1.w);
        acc2.x = fmaf(x2, fmaf(e2.x, s.x, m.x), acc2.x);
        acc2.y = fmaf(x2, fmaf(e2.y, s.y, m.y), acc2.y);
        acc2.z = fmaf(x2, fmaf(e2.z, s.z, m.z), acc2.z);
        acc2.w = fmaf(x2, fmaf(e2.w, s.w, m.w), acc2.w);
        acc3.x = fmaf(x3, fmaf(e3.x, s.x, m.x), acc3.x);
        acc3.y = fmaf(x3, fmaf(e3.y, s.y, m.y), acc3.y);
        acc3.z = fmaf(x3, fmaf(e3.z, s.z, m.z), acc3.z);
        acc3.w = fmaf(x3, fmaf(e3.w, s.w, m.w), acc3.w);
    }

    float* base = partial + ((size_t)iblk * BB) * OUTD + o;
    *(float4*)(base + (size_t)(b0 + 0) * OUTD) = acc0;
    *(float4*)(base + (size_t)(b0 + 1) * OUTD) = acc1;
    *(float4*)(base + (size_t)(b0 + 2) * OUTD) = acc2;
    *(float4*)(base + (size_t)(b0 + 3) * OUTD) = acc3;
}

// out[b,o] = sum_is partial[is,b,o] + eps_bias[b,o]*softplus(ro_bias[o]) + mu_bias[o]
__global__ __launch_bounds__(256) void finalize(
    const float* __restrict__ partial, const float* __restrict__ eps_bias,
    const float* __restrict__ mu_bias, const float* __restrict__ ro_bias,
    float* __restrict__ out) {
    int idx = blockIdx.x * 256 + threadIdx.x;  // float4 index over B*OUT/4
    int p = idx * 4;
    int o = p & (OUTD - 1);

    float4 acc = {0.f, 0.f, 0.f, 0.f};
#pragma unroll
    for (int is = 0; is < ISPLIT; ++is) {
        float4 a = *(const float4*)(partial + (size_t)is * BB * OUTD + p);
        acc.x += a.x;
        acc.y += a.y;
        acc.z += a.z;
        acc.w += a.w;
    }
    float4 eb = *(const float4*)(eps_bias + p);
    float4 rb = *(const float4*)(ro_bias + o);
    float4 mb = *(const float4*)(mu_bias + o);

    float4 r;
    r.x = acc.x + eb.x * softplus(rb.x) + mb.x;
    r.y = acc.y + eb.y * softplus(rb.y) + mb.y;
    r.z = acc.z + eb.z * softplus(rb.z) + mb.z;
    r.w = acc.w + eb.w * softplus(rb.w) + mb.w;
    ((float4*)out)[idx] = r;
}

extern "C" void kernel_launch(void* const* d_in, const int* in_sizes, int n_in,
                              void* d_out, int out_size, void* d_ws, size_t ws_size,
                              hipStream_t stream) {
    const float* x = (const float*)d_in[0];
    const float* eps = (const float*)d_in[1];
    const float* eps_bias = (const float*)d_in[2];
    const float* mu = (const float*)d_in[3];
    const float* ro = (const float*)d_in[4];
    const float* mu_bias = (const float*)d_in[5];
    const float* ro_bias = (const float*)d_in[6];
    float* out = (float*)d_out;

    float* sm = (float*)d_ws;                            // 2*IN*OUT floats = 8 MB
    float* partial = sm + (size_t)2 * IN * OUTD;         // ISPLIT*B*OUT floats = 8 MB

    prep_sm<<<(IN * OUTD / 4) / 256, 256, 0, stream>>>(ro, mu, sm);

    bayes_main<<<512, 256, 0, stream>>>(x, eps, sm, partial);

    finalize<<<(BB * OUTD / 4) / 256, 256, 0, stream>>>(partial, eps_bias, mu_bias,
                                                        ro_bias, out);
}

// Round 11
// 94.068 us; speedup vs baseline: 1.1774x; 1.1774x over previous
//
#include <hip/hip_runtime.h>
#include <math.h>

#define BB 128
#define IN 1024
#define OUTD 1024
#define ISPLIT 16
#define ICHUNK (IN / ISPLIT)   // 64

typedef float f4v __attribute__((ext_vector_type(4)));

__device__ __forceinline__ float softplus(float r) {
    // stable: log(1+exp(r)) = max(r,0) + log1p(exp(-|r|))
    return fmaxf(r, 0.0f) + log1pf(expf(-fabsf(r)));
}

// fast softplus for the inner loop: native exp/log, ample accuracy here
__device__ __forceinline__ float softplus_fast(float r) {
    float e = __expf(-fabsf(r));
    return fmaxf(r, 0.0f) + __logf(1.0f + e);
}

// Main: block covers b0..b0+15, o0..o0+255, i0..i0+ICHUNK-1 (R9 structure).
// tid = (bsub:2)<<6 | oq:6. Thread owns float4 at o = o0+oq*4 and
// accumulates 4 b's: b = b0 + bsub + 4k (4 eps streams/thread).
// sigma = softplus(ro) computed INLINE (no prep kernel, no sm buffer):
// ro/mu slices are XCD-owned (8 slices x 128 KB = 1 MB/XCD) -> L2-resident,
// fetched from HBM once; softplus recompute is ~34M quads, hidden under BW.
__global__ __launch_bounds__(256, 2) void bayes_main(
    const float* __restrict__ x, const float* __restrict__ eps,
    const float* __restrict__ ro, const float* __restrict__ mu,
    float* __restrict__ partial) {
    __shared__ float xs[16][ICHUNK];
    const int tid = threadIdx.x;

    // bijective decomposition; perf-only assumption bid%8 = XCD
    const int bid = blockIdx.x;          // [0,512)
    const int xcd = bid & 7;
    const int t = bid >> 3;              // [0,64)
    const int s_local = t & 7;
    const int bblk = t >> 3;             // [0,8)
    const int slice = s_local * 8 + xcd; // [0,64)
    const int oblk = slice & 3;
    const int iblk = slice >> 2;         // [0,16)
    const int b0 = bblk * 16;
    const int o0 = oblk * 256;
    const int i0 = iblk * ICHUNK;

    // stage x[b0..b0+15, i0..i0+ICHUNK-1] into LDS (1024 floats)
    for (int tt = tid; tt < 16 * ICHUNK; tt += 256) {
        int bb = tt / ICHUNK, ii = tt % ICHUNK;
        xs[bb][ii] = x[(size_t)(b0 + bb) * IN + i0 + ii];
    }
    __syncthreads();

    const int oq = tid & 63;
    const int bsub = tid >> 6;
    const int o = o0 + oq * 4;

    const float4* rp = (const float4*)(ro + (size_t)i0 * OUTD + o);
    const float4* mp = (const float4*)(mu + (size_t)i0 * OUTD + o);
    const f4v* e0p =
        (const f4v*)(eps + ((size_t)(b0 + bsub) * IN + i0) * OUTD + o);
    const f4v* e1p =
        (const f4v*)(eps + ((size_t)(b0 + bsub + 4) * IN + i0) * OUTD + o);
    const f4v* e2p =
        (const f4v*)(eps + ((size_t)(b0 + bsub + 8) * IN + i0) * OUTD + o);
    const f4v* e3p =
        (const f4v*)(eps + ((size_t)(b0 + bsub + 12) * IN + i0) * OUTD + o);

    float4 acc0 = {0.f, 0.f, 0.f, 0.f};
    float4 acc1 = {0.f, 0.f, 0.f, 0.f};
    float4 acc2 = {0.f, 0.f, 0.f, 0.f};
    float4 acc3 = {0.f, 0.f, 0.f, 0.f};

#pragma unroll 4
    for (int ii = 0; ii < ICHUNK; ++ii) {
        float4 r = rp[(size_t)ii * (OUTD / 4)];
        float4 m = mp[(size_t)ii * (OUTD / 4)];
        f4v e0 = __builtin_nontemporal_load(e0p + (size_t)ii * (OUTD / 4));
        f4v e1 = __builtin_nontemporal_load(e1p + (size_t)ii * (OUTD / 4));
        f4v e2 = __builtin_nontemporal_load(e2p + (size_t)ii * (OUTD / 4));
        f4v e3 = __builtin_nontemporal_load(e3p + (size_t)ii * (OUTD / 4));
        float4 s;
        s.x = softplus_fast(r.x);
        s.y = softplus_fast(r.y);
        s.z = softplus_fast(r.z);
        s.w = softplus_fast(r.w);
        float x0 = xs[bsub][ii];
        float x1 = xs[bsub + 4][ii];
        float x2 = xs[bsub + 8][ii];
        float x3 = xs[bsub + 12][ii];
        acc0.x = fmaf(x0, fmaf(e0.x, s.x, m.x), acc0.x);
        acc0.y = fmaf(x0, fmaf(e0.y, s.y, m.y), acc0.y);
        acc0.z = fmaf(x0, fmaf(e0.z, s.z, m.z), acc0.z);
        acc0.w = fmaf(x0, fmaf(e0.w, s.w, m.w), acc0.w);
        acc1.x = fmaf(x1, fmaf(e1.x, s.x, m.x), acc1.x);
        acc1.y = fmaf(x1, fmaf(e1.y, s.y, m.y), acc1.y);
        acc1.z = fmaf(x1, fmaf(e1.z, s.z, m.z), acc1.z);
        acc1.w = fmaf(x1, fmaf(e1.w, s.w, m.w), acc1.w);
        acc2.x = fmaf(x2, fmaf(e2.x, s.x, m.x), acc2.x);
        acc2.y = fmaf(x2, fmaf(e2.y, s.y, m.y), acc2.y);
        acc2.z = fmaf(x2, fmaf(e2.z, s.z, m.z), acc2.z);
        acc2.w = fmaf(x2, fmaf(e2.w, s.w, m.w), acc2.w);
        acc3.x = fmaf(x3, fmaf(e3.x, s.x, m.x), acc3.x);
        acc3.y = fmaf(x3, fmaf(e3.y, s.y, m.y), acc3.y);
        acc3.z = fmaf(x3, fmaf(e3.z, s.z, m.z), acc3.z);
        acc3.w = fmaf(x3, fmaf(e3.w, s.w, m.w), acc3.w);
    }

    float* base = partial + ((size_t)iblk * BB) * OUTD + o;
    *(float4*)(base + (size_t)(b0 + bsub) * OUTD) = acc0;
    *(float4*)(base + (size_t)(b0 + bsub + 4) * OUTD) = acc1;
    *(float4*)(base + (size_t)(b0 + bsub + 8) * OUTD) = acc2;
    *(float4*)(base + (size_t)(b0 + bsub + 12) * OUTD) = acc3;
}

// out[b,o] = sum_is partial[is,b,o] + eps_bias[b,o]*softplus(ro_bias[o]) + mu_bias[o]
__global__ __launch_bounds__(256) void finalize(
    const float* __restrict__ partial, const float* __restrict__ eps_bias,
    const float* __restrict__ mu_bias, const float* __restrict__ ro_bias,
    float* __restrict__ out) {
    int idx = blockIdx.x * 256 + threadIdx.x;  // float4 index over B*OUT/4
    int p = idx * 4;
    int o = p & (OUTD - 1);

    float4 acc = {0.f, 0.f, 0.f, 0.f};
#pragma unroll
    for (int is = 0; is < ISPLIT; ++is) {
        float4 a = *(const float4*)(partial + (size_t)is * BB * OUTD + p);
        acc.x += a.x;
        acc.y += a.y;
        acc.z += a.z;
        acc.w += a.w;
    }
    float4 eb = *(const float4*)(eps_bias + p);
    float4 rb = *(const float4*)(ro_bias + o);
    float4 mb = *(const float4*)(mu_bias + o);

    float4 r;
    r.x = acc.x + eb.x * softplus(rb.x) + mb.x;
    r.y = acc.y + eb.y * softplus(rb.y) + mb.y;
    r.z = acc.z + eb.z * softplus(rb.z) + mb.z;
    r.w = acc.w + eb.w * softplus(rb.w) + mb.w;
    ((float4*)out)[idx] = r;
}

extern "C" void kernel_launch(void* const* d_in, const int* in_sizes, int n_in,
                              void* d_out, int out_size, void* d_ws, size_t ws_size,
                              hipStream_t stream) {
    const float* x = (const float*)d_in[0];
    const float* eps = (const float*)d_in[1];
    const float* eps_bias = (const float*)d_in[2];
    const float* mu = (const float*)d_in[3];
    const float* ro = (const float*)d_in[4];
    const float* mu_bias = (const float*)d_in[5];
    const float* ro_bias = (const float*)d_in[6];
    float* out = (float*)d_out;

    float* partial = (float*)d_ws;  // ISPLIT*B*OUT floats = 8 MB

    bayes_main<<<512, 256, 0, stream>>>(x, eps, ro, mu, partial);

    finalize<<<(BB * OUTD / 4) / 256, 256, 0, stream>>>(partial, eps_bias, mu_bias,
                                                        ro_bias, out);
}